// Round 1
// baseline (657.703 us; speedup 1.0000x reference)
//
#include <hip/hip_runtime.h>
#include <hip/hip_bf16.h>

// GhostLinear: C[M][N] = x[M][K] @ (lut[idx[N][K]] * scale[N])^T
// M = B*S = 8192, N = OUT_F = 4096, K = IN_F = 4096, fp32 in/out.
// Strategy: dequant W -> bf16, convert x -> bf16, then m97-style MFMA GEMM.

#define M_DIM 8192
#define N_DIM 4096
#define K_DIM 4096
#define BM 128
#define BN 128
#define BK 32

typedef __bf16 bf16x8 __attribute__((ext_vector_type(8)));
typedef float floatx4 __attribute__((ext_vector_type(4)));
typedef unsigned short ushortx8 __attribute__((ext_vector_type(8)));

__device__ __forceinline__ unsigned short f2bf(float f) {
    return __builtin_bit_cast(unsigned short, (__bf16)f);   // RNE fptrunc
}

// Async global->LDS, 16B per lane. LDS dest = wave-uniform base + lane*16.
__device__ __forceinline__ void async_load16(const void* g, void* l) {
    auto gp = reinterpret_cast<const __attribute__((address_space(1))) void*>(
        reinterpret_cast<unsigned long long>(g));
    auto lp = reinterpret_cast<__attribute__((address_space(3))) void*>(
        static_cast<unsigned int>(reinterpret_cast<unsigned long long>(l)));
    __builtin_amdgcn_global_load_lds(gp, lp, 16, 0, 0);
}

// ---------------- kernel 1: x fp32 -> bf16 ----------------
__global__ __launch_bounds__(256) void convert_x(const float* __restrict__ x,
                                                 unsigned short* __restrict__ xb) {
    size_t i = ((size_t)blockIdx.x * 256 + threadIdx.x) * 8;
    float4 a = *(const float4*)(x + i);
    float4 b = *(const float4*)(x + i + 4);
    ushortx8 v;
    v[0] = f2bf(a.x); v[1] = f2bf(a.y); v[2] = f2bf(a.z); v[3] = f2bf(a.w);
    v[4] = f2bf(b.x); v[5] = f2bf(b.y); v[6] = f2bf(b.z); v[7] = f2bf(b.w);
    *(ushortx8*)(xb + i) = v;
}

// ---------------- kernel 2: dequant W -> bf16 [N][K] ----------------
__global__ __launch_bounds__(256) void dequant_w(const int* __restrict__ idx,
                                                 const float* __restrict__ scale,
                                                 const float* __restrict__ lut,
                                                 unsigned short* __restrict__ wb) {
    __shared__ float slut[256];
    if (threadIdx.x < 256) slut[threadIdx.x] = lut[threadIdx.x];
    __syncthreads();
    size_t i = ((size_t)blockIdx.x * 256 + threadIdx.x) * 8;   // 8 elems, same row
    int row = (int)(i >> 12);                                   // / K_DIM
    float s = scale[row];
    int4 i0 = *(const int4*)(idx + i);
    int4 i1 = *(const int4*)(idx + i + 4);
    ushortx8 v;
    v[0] = f2bf(slut[i0.x] * s); v[1] = f2bf(slut[i0.y] * s);
    v[2] = f2bf(slut[i0.z] * s); v[3] = f2bf(slut[i0.w] * s);
    v[4] = f2bf(slut[i1.x] * s); v[5] = f2bf(slut[i1.y] * s);
    v[6] = f2bf(slut[i1.z] * s); v[7] = f2bf(slut[i1.w] * s);
    *(ushortx8*)(wb + i) = v;
}

// ---------------- kernel 3: bf16 MFMA GEMM (m97 structure) ----------------
// A[M][K] bf16 row-major, Bw[N][K] bf16 row-major (i.e. B^T), C[M][N] fp32.
__global__ __launch_bounds__(256) void gemm_bf16(const unsigned short* __restrict__ A,
                                                 const unsigned short* __restrict__ Bw,
                                                 float* __restrict__ C) {
    __shared__ __align__(16) unsigned short As[BM * BK];   // 8 KB
    __shared__ __align__(16) unsigned short Bs[BN * BK];   // 8 KB

    const int t    = threadIdx.x;
    const int wave = t >> 6;
    const int lane = t & 63;
    const int m0   = blockIdx.y * BM;
    const int n0   = blockIdx.x * BN;

    const int mw   = (wave >> 1) * 64;   // wave's m offset in tile
    const int nw   = (wave & 1) * 64;    // wave's n offset in tile
    const int quad = lane >> 4;          // 0..3
    const int lcol = lane & 15;

    floatx4 acc[4][4];
#pragma unroll
    for (int i = 0; i < 4; i++)
#pragma unroll
        for (int j = 0; j < 4; j++) acc[i][j] = (floatx4)0.0f;

    // staging: 512 chunks of 8 bf16 (16B) per tile; thread t does chunks t and t+256
    const int r0 = t >> 2;             // row 0..63 (call 0), +64 for call 1
    const int c0 = (t & 3) * 8;        // k offset within tile
    unsigned short* AsB0 = As + wave * 512;          // wave-uniform LDS bases
    unsigned short* AsB1 = As + 2048 + wave * 512;
    unsigned short* BsB0 = Bs + wave * 512;
    unsigned short* BsB1 = Bs + 2048 + wave * 512;

    const unsigned short* aG = A + (size_t)m0 * K_DIM;
    const unsigned short* bG = Bw + (size_t)n0 * K_DIM;

    for (int k0 = 0; k0 < K_DIM; k0 += BK) {
        async_load16(aG + (size_t)r0 * K_DIM + k0 + c0, AsB0);
        async_load16(aG + (size_t)(r0 + 64) * K_DIM + k0 + c0, AsB1);
        async_load16(bG + (size_t)r0 * K_DIM + k0 + c0, BsB0);
        async_load16(bG + (size_t)(r0 + 64) * K_DIM + k0 + c0, BsB1);
        __syncthreads();   // compiler drains vmcnt before s_barrier

        bf16x8 a[4], b[4];
#pragma unroll
        for (int mt = 0; mt < 4; mt++)
            a[mt] = *(const bf16x8*)(As + (mw + mt * 16 + lcol) * BK + quad * 8);
#pragma unroll
        for (int nt = 0; nt < 4; nt++)
            b[nt] = *(const bf16x8*)(Bs + (nw + nt * 16 + lcol) * BK + quad * 8);

#pragma unroll
        for (int mt = 0; mt < 4; mt++)
#pragma unroll
            for (int nt = 0; nt < 4; nt++)
                acc[mt][nt] = __builtin_amdgcn_mfma_f32_16x16x32_bf16(
                    a[mt], b[nt], acc[mt][nt], 0, 0, 0);

        __syncthreads();
    }

    // epilogue: C row = m0+mw+mt*16+quad*4+r, col = n0+nw+nt*16+lcol
#pragma unroll
    for (int mt = 0; mt < 4; mt++) {
#pragma unroll
        for (int r = 0; r < 4; r++) {
            int row = m0 + mw + mt * 16 + quad * 4 + r;
            float* cr = C + (size_t)row * N_DIM + n0 + nw + lcol;
#pragma unroll
            for (int nt = 0; nt < 4; nt++)
                cr[nt * 16] = acc[mt][nt][r];
        }
    }
}

// ---------------- fallback: correct fp32 tiled GEMM (no workspace) ----------------
__global__ __launch_bounds__(256) void gemm_fallback(const float* __restrict__ x,
                                                     const int* __restrict__ idx,
                                                     const float* __restrict__ scale,
                                                     const float* __restrict__ lut,
                                                     float* __restrict__ C) {
    __shared__ float xs[16][17];
    __shared__ float wsm[16][17];
    const int tx = threadIdx.x & 15;
    const int ty = threadIdx.x >> 4;
    const int m = blockIdx.y * 16 + ty;
    const int n = blockIdx.x * 16 + tx;
    float acc = 0.f;
    for (int k0 = 0; k0 < K_DIM; k0 += 16) {
        xs[ty][tx] = x[(size_t)m * K_DIM + k0 + tx];
        int wrow = blockIdx.x * 16 + ty;
        wsm[ty][tx] = lut[idx[(size_t)wrow * K_DIM + k0 + tx]] * scale[wrow];
        __syncthreads();
#pragma unroll
        for (int kk = 0; kk < 16; kk++) acc += xs[ty][kk] * wsm[tx][kk];
        __syncthreads();
    }
    C[(size_t)m * N_DIM + n] = acc;
}

extern "C" void kernel_launch(void* const* d_in, const int* in_sizes, int n_in,
                              void* d_out, int out_size, void* d_ws, size_t ws_size,
                              hipStream_t stream) {
    const float* x     = (const float*)d_in[0];
    const int*   gidx  = (const int*)d_in[1];
    const float* scale = (const float*)d_in[2];
    const float* lut   = (const float*)d_in[3];
    float*       out   = (float*)d_out;

    const size_t needA = (size_t)M_DIM * K_DIM * sizeof(unsigned short); // 64 MB
    const size_t needW = (size_t)N_DIM * K_DIM * sizeof(unsigned short); // 32 MB

    if (ws_size >= needA + needW) {
        unsigned short* Ab = (unsigned short*)d_ws;
        unsigned short* Wb = Ab + (size_t)M_DIM * K_DIM;
        convert_x<<<(M_DIM * (size_t)K_DIM) / (256 * 8), 256, 0, stream>>>(x, Ab);
        dequant_w<<<(N_DIM * (size_t)K_DIM) / (256 * 8), 256, 0, stream>>>(gidx, scale, lut, Wb);
        dim3 grid(N_DIM / BN, M_DIM / BM);
        gemm_bf16<<<grid, 256, 0, stream>>>(Ab, Wb, out);
    } else {
        dim3 grid(N_DIM / 16, M_DIM / 16);
        gemm_fallback<<<grid, 256, 0, stream>>>(x, gidx, scale, lut, out);
    }
}

// Round 3
// 621.908 us; speedup vs baseline: 1.0576x; 1.0576x over previous
//
#include <hip/hip_runtime.h>
#include <hip/hip_bf16.h>

// GhostLinear: C[M][N] = x[M][K] @ (lut[idx[N][K]] * scale[N])^T
// M = B*S = 8192, N = OUT_F = 4096, K = IN_F = 4096, fp32 in/out.
// R3: supertile block swizzle for L2 locality, fused pre-pass, nt C stores.
//     (R2 compile fix: clang ext_vector types for nontemporal builtins.)

#define M_DIM 8192
#define N_DIM 4096
#define K_DIM 4096
#define BM 128
#define BN 128
#define BK 32

typedef __bf16 bf16x8 __attribute__((ext_vector_type(8)));
typedef float floatx4 __attribute__((ext_vector_type(4)));
typedef int intx4 __attribute__((ext_vector_type(4)));
typedef unsigned short ushortx8 __attribute__((ext_vector_type(8)));

__device__ __forceinline__ unsigned short f2bf(float f) {
    return __builtin_bit_cast(unsigned short, (__bf16)f);   // RNE fptrunc
}

// Async global->LDS, 16B per lane. LDS dest = wave-uniform base + lane*16.
__device__ __forceinline__ void async_load16(const void* g, void* l) {
    auto gp = reinterpret_cast<const __attribute__((address_space(1))) void*>(
        reinterpret_cast<unsigned long long>(g));
    auto lp = reinterpret_cast<__attribute__((address_space(3))) void*>(
        static_cast<unsigned int>(reinterpret_cast<unsigned long long>(l)));
    __builtin_amdgcn_global_load_lds(gp, lp, 16, 0, 0);
}

// ---------------- fused pre-pass ----------------
// blocks [0, 16384): x fp32 -> bf16 (8 elems/thread)
// blocks [16384, 24576): W = lut[idx]*scale -> bf16 (8 elems/thread)
// nontemporal loads on read-once streams (x, idx) to keep L2 for the ws writes.
__global__ __launch_bounds__(256) void prep(const float* __restrict__ x,
                                            unsigned short* __restrict__ xb,
                                            const int* __restrict__ idx,
                                            const float* __restrict__ scale,
                                            const float* __restrict__ lut,
                                            unsigned short* __restrict__ wb) {
    __shared__ float slut[256];
    if (blockIdx.x < 16384) {
        size_t i = ((size_t)blockIdx.x * 256 + threadIdx.x) * 8;
        floatx4 a = __builtin_nontemporal_load((const floatx4*)(x + i));
        floatx4 b = __builtin_nontemporal_load((const floatx4*)(x + i + 4));
        ushortx8 v;
        v[0] = f2bf(a[0]); v[1] = f2bf(a[1]); v[2] = f2bf(a[2]); v[3] = f2bf(a[3]);
        v[4] = f2bf(b[0]); v[5] = f2bf(b[1]); v[6] = f2bf(b[2]); v[7] = f2bf(b[3]);
        *(ushortx8*)(xb + i) = v;
    } else {
        if (threadIdx.x < 256) slut[threadIdx.x] = lut[threadIdx.x];
        __syncthreads();
        size_t i = ((size_t)(blockIdx.x - 16384) * 256 + threadIdx.x) * 8;
        int row = (int)(i >> 12);                       // / K_DIM (8 elems same row)
        float s = scale[row];
        intx4 i0 = __builtin_nontemporal_load((const intx4*)(idx + i));
        intx4 i1 = __builtin_nontemporal_load((const intx4*)(idx + i + 4));
        ushortx8 v;
        v[0] = f2bf(slut[i0[0]] * s); v[1] = f2bf(slut[i0[1]] * s);
        v[2] = f2bf(slut[i0[2]] * s); v[3] = f2bf(slut[i0[3]] * s);
        v[4] = f2bf(slut[i1[0]] * s); v[5] = f2bf(slut[i1[1]] * s);
        v[6] = f2bf(slut[i1[2]] * s); v[7] = f2bf(slut[i1[3]] * s);
        *(ushortx8*)(wb + i) = v;
    }
}

// ---------------- bf16 MFMA GEMM (m97 structure + supertile swizzle) ----------------
// A[M][K] bf16 row-major, Bw[N][K] bf16 row-major (i.e. B^T), C[M][N] fp32.
// 1D grid of 2048 blocks. Supertile = 8 m-blocks x 4 n-blocks (32 ids):
//   per-XCD slice (every 8th id) = 1 A-slab + 4 W-slabs ~ 5 MB ~ L2.
// Supertiles ordered m-major: consecutive supertiles reuse the same 4 W-slabs.
__global__ __launch_bounds__(256) void gemm_bf16(const unsigned short* __restrict__ A,
                                                 const unsigned short* __restrict__ Bw,
                                                 float* __restrict__ C) {
    __shared__ __align__(16) unsigned short As[BM * BK];   // 8 KB
    __shared__ __align__(16) unsigned short Bs[BN * BK];   // 8 KB

    const int id = blockIdx.x;
    const int st = id >> 5;          // supertile 0..63 (8 stm x 8 stn)
    const int li = id & 31;          // lane in supertile
    const int m_blk = (st & 7) * 8 + (li & 7);    // 0..63
    const int n_blk = (st >> 3) * 4 + (li >> 3);  // 0..31
    const int m0 = m_blk * BM;
    const int n0 = n_blk * BN;

    const int t    = threadIdx.x;
    const int wave = t >> 6;
    const int lane = t & 63;

    const int mw   = (wave >> 1) * 64;   // wave's m offset in tile
    const int nw   = (wave & 1) * 64;    // wave's n offset in tile
    const int quad = lane >> 4;          // 0..3
    const int lcol = lane & 15;

    floatx4 acc[4][4];
#pragma unroll
    for (int i = 0; i < 4; i++)
#pragma unroll
        for (int j = 0; j < 4; j++) acc[i][j] = (floatx4)0.0f;

    // staging: 512 chunks of 8 bf16 (16B) per tile
    const int r0 = t >> 2;             // row 0..63 (call 0), +64 for call 1
    const int c0 = (t & 3) * 8;        // k offset within tile
    unsigned short* AsB0 = As + wave * 512;          // wave-uniform LDS bases
    unsigned short* AsB1 = As + 2048 + wave * 512;
    unsigned short* BsB0 = Bs + wave * 512;
    unsigned short* BsB1 = Bs + 2048 + wave * 512;

    const unsigned short* aG = A + (size_t)m0 * K_DIM;
    const unsigned short* bG = Bw + (size_t)n0 * K_DIM;

    for (int k0 = 0; k0 < K_DIM; k0 += BK) {
        async_load16(aG + (size_t)r0 * K_DIM + k0 + c0, AsB0);
        async_load16(aG + (size_t)(r0 + 64) * K_DIM + k0 + c0, AsB1);
        async_load16(bG + (size_t)r0 * K_DIM + k0 + c0, BsB0);
        async_load16(bG + (size_t)(r0 + 64) * K_DIM + k0 + c0, BsB1);
        __syncthreads();   // compiler drains vmcnt before s_barrier

        bf16x8 a[4], b[4];
#pragma unroll
        for (int mt = 0; mt < 4; mt++)
            a[mt] = *(const bf16x8*)(As + (mw + mt * 16 + lcol) * BK + quad * 8);
#pragma unroll
        for (int nt = 0; nt < 4; nt++)
            b[nt] = *(const bf16x8*)(Bs + (nw + nt * 16 + lcol) * BK + quad * 8);

#pragma unroll
        for (int mt = 0; mt < 4; mt++)
#pragma unroll
            for (int nt = 0; nt < 4; nt++)
                acc[mt][nt] = __builtin_amdgcn_mfma_f32_16x16x32_bf16(
                    a[mt], b[nt], acc[mt][nt], 0, 0, 0);

        __syncthreads();
    }

    // epilogue: C row = m0+mw+mt*16+quad*4+r, col = n0+nw+nt*16+lcol
    // nontemporal: C is write-once, keep L2 for A/W tiles.
#pragma unroll
    for (int mt = 0; mt < 4; mt++) {
#pragma unroll
        for (int r = 0; r < 4; r++) {
            int row = m0 + mw + mt * 16 + quad * 4 + r;
            float* cr = C + (size_t)row * N_DIM + n0 + nw + lcol;
#pragma unroll
            for (int nt = 0; nt < 4; nt++)
                __builtin_nontemporal_store(acc[mt][nt][r], cr + nt * 16);
        }
    }
}

// ---------------- fallback: correct fp32 tiled GEMM (no workspace) ----------------
__global__ __launch_bounds__(256) void gemm_fallback(const float* __restrict__ x,
                                                     const int* __restrict__ idx,
                                                     const float* __restrict__ scale,
                                                     const float* __restrict__ lut,
                                                     float* __restrict__ C) {
    __shared__ float xs[16][17];
    __shared__ float wsm[16][17];
    const int tx = threadIdx.x & 15;
    const int ty = threadIdx.x >> 4;
    const int m = blockIdx.y * 16 + ty;
    const int n = blockIdx.x * 16 + tx;
    float acc = 0.f;
    for (int k0 = 0; k0 < K_DIM; k0 += 16) {
        xs[ty][tx] = x[(size_t)m * K_DIM + k0 + tx];
        int wrow = blockIdx.x * 16 + ty;
        wsm[ty][tx] = lut[idx[(size_t)wrow * K_DIM + k0 + tx]] * scale[wrow];
        __syncthreads();
#pragma unroll
        for (int kk = 0; kk < 16; kk++) acc += xs[ty][kk] * wsm[tx][kk];
        __syncthreads();
    }
    C[(size_t)m * N_DIM + n] = acc;
}

extern "C" void kernel_launch(void* const* d_in, const int* in_sizes, int n_in,
                              void* d_out, int out_size, void* d_ws, size_t ws_size,
                              hipStream_t stream) {
    const float* x     = (const float*)d_in[0];
    const int*   gidx  = (const int*)d_in[1];
    const float* scale = (const float*)d_in[2];
    const float* lut   = (const float*)d_in[3];
    float*       out   = (float*)d_out;

    const size_t needA = (size_t)M_DIM * K_DIM * sizeof(unsigned short); // 64 MB
    const size_t needW = (size_t)N_DIM * K_DIM * sizeof(unsigned short); // 32 MB

    if (ws_size >= needA + needW) {
        unsigned short* Ab = (unsigned short*)d_ws;
        unsigned short* Wb = Ab + (size_t)M_DIM * K_DIM;
        // fused pre-pass: 16384 convert blocks + 8192 dequant blocks
        prep<<<24576, 256, 0, stream>>>(x, Ab, gidx, scale, lut, Wb);
        gemm_bf16<<<(M_DIM / BM) * (N_DIM / BN), 256, 0, stream>>>(Ab, Wb, out);
    } else {
        dim3 grid(N_DIM / 16, M_DIM / 16);
        gemm_fallback<<<grid, 16 * 16, 0, stream>>>(x, gidx, scale, lut, out);
    }
}

// Round 4
// 531.126 us; speedup vs baseline: 1.2383x; 1.1709x over previous
//
#include <hip/hip_runtime.h>
#include <hip/hip_bf16.h>

// GhostLinear: C[M][N] = x[M][K] @ (lut[idx[N][K]] * scale[N])^T
// M = B*S = 8192, N = OUT_F = 4096, K = IN_F = 4096, fp32 in/out.
// R4: BK=64 (one barrier pair per 64-K, 32 MFMA/barrier), global-source
//     chunk rotation so the 128B row stride stays bank-even without LDS
//     padding (global_load_lds dest must be contiguous).

#define M_DIM 8192
#define N_DIM 4096
#define K_DIM 4096
#define BM 128
#define BN 128
#define BK 64

typedef __bf16 bf16x8 __attribute__((ext_vector_type(8)));
typedef float floatx4 __attribute__((ext_vector_type(4)));
typedef int intx4 __attribute__((ext_vector_type(4)));
typedef unsigned short ushortx8 __attribute__((ext_vector_type(8)));

__device__ __forceinline__ unsigned short f2bf(float f) {
    return __builtin_bit_cast(unsigned short, (__bf16)f);   // RNE fptrunc
}

// Async global->LDS, 16B per lane. LDS dest = wave-uniform base + lane*16.
__device__ __forceinline__ void async_load16(const void* g, void* l) {
    auto gp = reinterpret_cast<const __attribute__((address_space(1))) void*>(
        reinterpret_cast<unsigned long long>(g));
    auto lp = reinterpret_cast<__attribute__((address_space(3))) void*>(
        static_cast<unsigned int>(reinterpret_cast<unsigned long long>(l)));
    __builtin_amdgcn_global_load_lds(gp, lp, 16, 0, 0);
}

// ---------------- fused pre-pass ----------------
// blocks [0, 16384): x fp32 -> bf16 (8 elems/thread)
// blocks [16384, 24576): W = lut[idx]*scale -> bf16 (8 elems/thread)
__global__ __launch_bounds__(256) void prep(const float* __restrict__ x,
                                            unsigned short* __restrict__ xb,
                                            const int* __restrict__ idx,
                                            const float* __restrict__ scale,
                                            const float* __restrict__ lut,
                                            unsigned short* __restrict__ wb) {
    __shared__ float slut[256];
    if (blockIdx.x < 16384) {
        size_t i = ((size_t)blockIdx.x * 256 + threadIdx.x) * 8;
        floatx4 a = __builtin_nontemporal_load((const floatx4*)(x + i));
        floatx4 b = __builtin_nontemporal_load((const floatx4*)(x + i + 4));
        ushortx8 v;
        v[0] = f2bf(a[0]); v[1] = f2bf(a[1]); v[2] = f2bf(a[2]); v[3] = f2bf(a[3]);
        v[4] = f2bf(b[0]); v[5] = f2bf(b[1]); v[6] = f2bf(b[2]); v[7] = f2bf(b[3]);
        *(ushortx8*)(xb + i) = v;
    } else {
        if (threadIdx.x < 256) slut[threadIdx.x] = lut[threadIdx.x];
        __syncthreads();
        size_t i = ((size_t)(blockIdx.x - 16384) * 256 + threadIdx.x) * 8;
        int row = (int)(i >> 12);                       // / K_DIM (8 elems same row)
        float s = scale[row];
        intx4 i0 = __builtin_nontemporal_load((const intx4*)(idx + i));
        intx4 i1 = __builtin_nontemporal_load((const intx4*)(idx + i + 4));
        ushortx8 v;
        v[0] = f2bf(slut[i0[0]] * s); v[1] = f2bf(slut[i0[1]] * s);
        v[2] = f2bf(slut[i0[2]] * s); v[3] = f2bf(slut[i0[3]] * s);
        v[4] = f2bf(slut[i1[0]] * s); v[5] = f2bf(slut[i1[1]] * s);
        v[6] = f2bf(slut[i1[2]] * s); v[7] = f2bf(slut[i1[3]] * s);
        *(ushortx8*)(wb + i) = v;
    }
}

// ---------------- bf16 MFMA GEMM, BK=64 ----------------
// A[M][K] bf16 row-major, Bw[N][K] bf16 row-major (B^T), C[M][N] fp32.
// LDS row r stores its 8 global 16B-chunks rotated: LDS chunk j = global
// chunk (j - r) & 7. Reader wants global chunk q -> LDS chunk (q + r) & 7,
// which distributes a full-wave b128 read evenly over all 32 banks.
__global__ __launch_bounds__(256) void gemm_bf16(const unsigned short* __restrict__ A,
                                                 const unsigned short* __restrict__ Bw,
                                                 float* __restrict__ C) {
    __shared__ __align__(16) unsigned short As[BM * BK];   // 16 KB
    __shared__ __align__(16) unsigned short Bs[BN * BK];   // 16 KB

    const int id = blockIdx.x;
    const int st = id >> 5;          // supertile 0..63 (8 stm x 8 stn)
    const int li = id & 31;
    const int m_blk = (st & 7) * 8 + (li & 7);    // 0..63
    const int n_blk = (st >> 3) * 4 + (li >> 3);  // 0..31
    const int m0 = m_blk * BM;
    const int n0 = n_blk * BN;

    const int t    = threadIdx.x;
    const int wave = t >> 6;
    const int lane = t & 63;

    const int mw   = (wave >> 1) * 64;   // wave's m offset in tile
    const int nw   = (wave & 1) * 64;    // wave's n offset in tile
    const int quad = lane >> 4;          // 0..3
    const int lcol = lane & 15;

    floatx4 acc[4][4];
#pragma unroll
    for (int i = 0; i < 4; i++)
#pragma unroll
        for (int j = 0; j < 4; j++) acc[i][j] = (floatx4)0.0f;

    // staging: per call, thread t stages row i*32 + (t>>3), LDS chunk t&7,
    // global chunk ((t&7) - row) & 7  (row & 7 == (t>>3) & 7).
    const int rr = t >> 3;                       // 0..31
    const int cc = t & 7;                        // LDS chunk
    const int sw = (((cc - rr) & 7) << 3);       // global k-offset (elems)
    // wave-uniform LDS base for call i: rows i*32 + wave*8 .. +7 contiguous
    unsigned short* AsB[4];
    unsigned short* BsB[4];
#pragma unroll
    for (int i = 0; i < 4; i++) {
        AsB[i] = As + (i * 32 + (wave << 3)) * BK;
        BsB[i] = Bs + (i * 32 + (wave << 3)) * BK;
    }

    const unsigned short* aG = A + (size_t)m0 * K_DIM;
    const unsigned short* bG = Bw + (size_t)n0 * K_DIM;

    for (int k0 = 0; k0 < K_DIM; k0 += BK) {
#pragma unroll
        for (int i = 0; i < 4; i++) {
            async_load16(aG + (size_t)(i * 32 + rr) * K_DIM + k0 + sw, AsB[i]);
            async_load16(bG + (size_t)(i * 32 + rr) * K_DIM + k0 + sw, BsB[i]);
        }
        __syncthreads();   // drains vmcnt; one drain per 64-K now

#pragma unroll
        for (int ks = 0; ks < 2; ks++) {
            bf16x8 a[4], b[4];
#pragma unroll
            for (int mt = 0; mt < 4; mt++) {
                int R = mw + mt * 16 + lcol;
                int ch = (quad + ks * 4 + R) & 7;          // swizzled LDS chunk
                a[mt] = *(const bf16x8*)(As + R * BK + ch * 8);
            }
#pragma unroll
            for (int nt = 0; nt < 4; nt++) {
                int R = nw + nt * 16 + lcol;
                int ch = (quad + ks * 4 + R) & 7;
                b[nt] = *(const bf16x8*)(Bs + R * BK + ch * 8);
            }
#pragma unroll
            for (int mt = 0; mt < 4; mt++)
#pragma unroll
                for (int nt = 0; nt < 4; nt++)
                    acc[mt][nt] = __builtin_amdgcn_mfma_f32_16x16x32_bf16(
                        a[mt], b[nt], acc[mt][nt], 0, 0, 0);
        }
        __syncthreads();
    }

    // epilogue: C row = m0+mw+mt*16+quad*4+r, col = n0+nw+nt*16+lcol
#pragma unroll
    for (int mt = 0; mt < 4; mt++) {
#pragma unroll
        for (int r = 0; r < 4; r++) {
            int row = m0 + mw + mt * 16 + quad * 4 + r;
            float* cr = C + (size_t)row * N_DIM + n0 + nw + lcol;
#pragma unroll
            for (int nt = 0; nt < 4; nt++)
                __builtin_nontemporal_store(acc[mt][nt][r], cr + nt * 16);
        }
    }
}

// ---------------- fallback: correct fp32 tiled GEMM (no workspace) ----------------
__global__ __launch_bounds__(256) void gemm_fallback(const float* __restrict__ x,
                                                     const int* __restrict__ idx,
                                                     const float* __restrict__ scale,
                                                     const float* __restrict__ lut,
                                                     float* __restrict__ C) {
    __shared__ float xs[16][17];
    __shared__ float wsm[16][17];
    const int tx = threadIdx.x & 15;
    const int ty = threadIdx.x >> 4;
    const int m = blockIdx.y * 16 + ty;
    const int n = blockIdx.x * 16 + tx;
    float acc = 0.f;
    for (int k0 = 0; k0 < K_DIM; k0 += 16) {
        xs[ty][tx] = x[(size_t)m * K_DIM + k0 + tx];
        int wrow = blockIdx.x * 16 + ty;
        wsm[ty][tx] = lut[idx[(size_t)wrow * K_DIM + k0 + tx]] * scale[wrow];
        __syncthreads();
#pragma unroll
        for (int kk = 0; kk < 16; kk++) acc += xs[ty][kk] * wsm[tx][kk];
        __syncthreads();
    }
    C[(size_t)m * N_DIM + n] = acc;
}

extern "C" void kernel_launch(void* const* d_in, const int* in_sizes, int n_in,
                              void* d_out, int out_size, void* d_ws, size_t ws_size,
                              hipStream_t stream) {
    const float* x     = (const float*)d_in[0];
    const int*   gidx  = (const int*)d_in[1];
    const float* scale = (const float*)d_in[2];
    const float* lut   = (const float*)d_in[3];
    float*       out   = (float*)d_out;

    const size_t needA = (size_t)M_DIM * K_DIM * sizeof(unsigned short); // 64 MB
    const size_t needW = (size_t)N_DIM * K_DIM * sizeof(unsigned short); // 32 MB

    if (ws_size >= needA + needW) {
        unsigned short* Ab = (unsigned short*)d_ws;
        unsigned short* Wb = Ab + (size_t)M_DIM * K_DIM;
        prep<<<24576, 256, 0, stream>>>(x, Ab, gidx, scale, lut, Wb);
        gemm_bf16<<<(M_DIM / BM) * (N_DIM / BN), 256, 0, stream>>>(Ab, Wb, out);
    } else {
        dim3 grid(N_DIM / 16, M_DIM / 16);
        gemm_fallback<<<grid, 16 * 16, 0, stream>>>(x, gidx, scale, lut, out);
    }
}